// Round 14
// baseline (929.198 us; speedup 1.0000x reference)
//
#include <hip/hip_runtime.h>
#include <hip/hip_fp16.h>
#include <math.h>

#define DIM 128
#define POOL_SPLIT 32  // partial-sum blocks per graph
#define BINSH 10       // 1024 nodes per dst-bin
#define EPB 16384      // edges per bin_k block
#define ALH 136        // gemm A-tile LDS row stride in halves
// Build discipline (R6): per-EDGE global atomics ping-pong cache lines across
// the 8 non-coherent XCD L2s — catastrophic. All per-edge counting in LDS.
// Agg model (R8-R13): random 128B-row gather from 12.8MB working set misses
// every 4MB XCD-L2 -> pinned at L3's ~4 TB/s random floor (~50us). Escape:
// SLICE-MAJOR T (8 x 16B slices) + slice = blockIdx&7 -> with round-robin
// block->XCD dispatch each XCD's slice working set is 1.6MB (L2-resident),
// and one wave-gather serves 16 edges (4B x 4 words/slice x 16 edges).

typedef __attribute__((ext_vector_type(8))) _Float16 half8;
typedef __attribute__((ext_vector_type(4))) float f32x4;
typedef __attribute__((ext_vector_type(2))) float f32x2;

// ---------------------------------------------------------------------------
// Graph build: bincount -> binscan -> bin -> rowcnt -> fill2
// ---------------------------------------------------------------------------

__global__ __launch_bounds__(256) void bincount_k(const int* __restrict__ dst,
                                                  int* __restrict__ binsize,
                                                  int E, int NBIN) {
    __shared__ int h[128];
    const int t = threadIdx.x;
    if (t < 128) h[t] = 0;
    __syncthreads();
    const int e0 = blockIdx.x * EPB;
    const int e1 = min(e0 + EPB, E);
    for (int e = e0 + t; e < e1; e += 256)
        atomicAdd(&h[dst[e] >> BINSH], 1);
    __syncthreads();
    if (t < NBIN && h[t]) atomicAdd(&binsize[t], h[t]);
}

__global__ void binscan2_k(const int* __restrict__ binsize, int* __restrict__ binbase,
                           int* __restrict__ bincur, int NBIN, int E) {
    __shared__ int s[128];
    const int t = threadIdx.x;   // 128 threads
    int v = (t < NBIN) ? binsize[t] : 0;
    s[t] = v;
    __syncthreads();
    for (int off = 1; off < 128; off <<= 1) {
        int u = (t >= off) ? s[t - off] : 0;
        __syncthreads();
        s[t] += u;
        __syncthreads();
    }
    int excl = s[t] - v;
    if (t < NBIN) { binbase[t] = excl; bincur[t * 16] = excl; }
    if (t == 0) binbase[NBIN] = E;
}

__global__ __launch_bounds__(256) void bin_k(const int* __restrict__ src,
                                             const int* __restrict__ dst,
                                             int* __restrict__ bincur,
                                             int2* __restrict__ tmp, int E, int NBIN) {
    __shared__ int cur[128];
    const int t = threadIdx.x;
    if (t < 128) cur[t] = 0;
    __syncthreads();
    const int e0 = blockIdx.x * EPB;
    const int e1 = min(e0 + EPB, E);
    for (int e = e0 + t; e < e1; e += 256)
        atomicAdd(&cur[dst[e] >> BINSH], 1);
    __syncthreads();
    if (t < NBIN) {
        int h = cur[t];
        cur[t] = h ? atomicAdd(&bincur[t * 16], h) : 0;
    }
    __syncthreads();
    for (int e = e0 + t; e < e1; e += 256) {
        int d = dst[e], s = src[e];
        int pos = atomicAdd(&cur[d >> BINSH], 1);
        tmp[pos] = make_int2(s, d);
    }
}

__global__ __launch_bounds__(256) void rowcnt_k(const int2* __restrict__ tmp,
                                                const int* __restrict__ binbase,
                                                int* __restrict__ rowptr,
                                                float* __restrict__ dis,
                                                int n, int E, int NBIN) {
    __shared__ int cnt[1 << BINSH];
    __shared__ int part[256];
    const int b = blockIdx.x, t = threadIdx.x;
    for (int i = t; i < (1 << BINSH); i += 256) cnt[i] = 0;
    __syncthreads();
    const int ebeg = binbase[b], eend = binbase[b + 1];
    for (int e = ebeg + t; e < eend; e += 256)
        atomicAdd(&cnt[tmp[e].y & ((1 << BINSH) - 1)], 1);
    __syncthreads();
    int cc[4];
    cc[0] = cnt[t * 4 + 0]; cc[1] = cnt[t * 4 + 1];
    cc[2] = cnt[t * 4 + 2]; cc[3] = cnt[t * 4 + 3];
    int s = cc[0] + cc[1] + cc[2] + cc[3];
    part[t] = s;
    __syncthreads();
    for (int off = 1; off < 256; off <<= 1) {
        int u = (t >= off) ? part[t - off] : 0;
        __syncthreads();
        part[t] += u;
        __syncthreads();
    }
    int off0 = ebeg + part[t] - s;
    int node0 = (b << BINSH) + t * 4;
    int pre = 0;
#pragma unroll
    for (int j = 0; j < 4; ++j) {
        int node = node0 + j;
        if (node < n) {
            rowptr[node] = off0 + pre;
            dis[node] = rsqrtf((float)(cc[j] + 1));
        }
        pre += cc[j];
    }
    if (b == NBIN - 1 && t == 0) rowptr[n] = E;
}

__global__ __launch_bounds__(256) void fill2_k(const int2* __restrict__ tmp,
                                               const int* __restrict__ rowptr,
                                               const float* __restrict__ dis,
                                               int2* __restrict__ ew, int n) {
    __shared__ int lcur[1 << BINSH];
    const int base_node = blockIdx.x << BINSH;
    const int t = threadIdx.x;
    for (int i = t; i < (1 << BINSH); i += 256)
        if (base_node + i < n) lcur[i] = rowptr[base_node + i];
    const int e_begin = rowptr[base_node];
    const int e_end   = rowptr[min(base_node + (1 << BINSH), n)];
    __syncthreads();
    for (int e = e_begin + t; e < e_end; e += 256) {
        int2 r = tmp[e];
        float w = dis[r.x] * dis[r.y];
        int q = atomicAdd(&lcur[r.y & ((1 << BINSH) - 1)], 1);
        ew[q] = make_int2(r.x, __float_as_int(w));
    }
}

// ---------------------------------------------------------------------------
// Weight pre-pack: conv_w (fp32 [k][col]) -> fp16 MFMA A-operand fragment order
// ---------------------------------------------------------------------------
__global__ void wpack_k(const float* __restrict__ conv_w, _Float16* __restrict__ bp) {
    int g = blockIdx.x * 256 + threadIdx.x;   // 3 * 2048
    if (g >= 3 * 2048) return;
    int l = g >> 11;
    int rem = g & 2047;
    int c = rem >> 8;
    int f = (rem >> 6) & 3;
    int lane = rem & 63;
    const float* W = conv_w + l * DIM * DIM;
    int kbase = f * 32 + (lane >> 4) * 8;
    int col = c * 16 + (lane & 15);
    _Float16* d = bp + ((size_t)l * 2048 + (size_t)(c * 4 + f) * 64 + lane) * 8;
#pragma unroll
    for (int j = 0; j < 8; ++j)
        d[j] = (_Float16)W[(kbase + j) * DIM + col];
}

// ---------------------------------------------------------------------------
// MFMA GEMM: T(fp8 e4m3, SLICE-MAJOR) = A[n,128] @ W ; fp32 accumulate.
// D^T via operand swap -> lane owns c-tile c's 4 consecutive cols = word
// `quad` of slice (c>>1? no): slice granularity is 16 dims = c-tile. Store:
// T32[(c*n + row)*4 + quad]  (16 rows/wave x 16B contiguous = 256B runs).
// ---------------------------------------------------------------------------
template <bool FP16IN>
__global__ __launch_bounds__(256) void gemm_k(const void* __restrict__ Ain,
                                              const _Float16* __restrict__ Bp,
                                              unsigned int* __restrict__ T32, int n) {
    __shared__ _Float16 Al[64 * ALH];
    const int t = threadIdx.x;
    const int r0 = blockIdx.x * 64;
    const int nrows = min(64, n - r0);

    if (FP16IN) {
        const _Float16* A = (const _Float16*)Ain;
        for (int idx = t; idx < 64 * 16; idx += 256) {
            int row = idx >> 4, c = idx & 15;
            half8 v = {};
            if (row < nrows) v = *(const half8*)(A + (size_t)(r0 + row) * DIM + c * 8);
            *(half8*)&Al[row * ALH + c * 8] = v;
        }
    } else {
        const float* A = (const float*)Ain;
        for (int idx = t; idx < 64 * 32; idx += 256) {
            int row = idx >> 5, c = idx & 31;
            float4 v = make_float4(0.f, 0.f, 0.f, 0.f);
            if (row < nrows) v = ((const float4*)(A + (size_t)(r0 + row) * DIM))[c];
            __half2 h01 = __floats2half2_rn(v.x, v.y);
            __half2 h23 = __floats2half2_rn(v.z, v.w);
            *(int2*)&Al[row * ALH + c * 4] = make_int2(*(int*)&h01, *(int*)&h23);
        }
    }
    __syncthreads();

    const int lane = t & 63;
    const int wave = t >> 6;
    const int quad = lane >> 4;
    const int m    = lane & 15;
    const int lrow = wave * 16 + m;
    const int row  = r0 + lrow;

    half8 a[4];
#pragma unroll
    for (int f = 0; f < 4; ++f)
        a[f] = *(const half8*)&Al[lrow * ALH + f * 32 + quad * 8];

    const half8* B8 = (const half8*)Bp;   // 32KB/layer, hot in L1
#pragma unroll
    for (int c = 0; c < 8; ++c) {
        f32x4 acc = {0.f, 0.f, 0.f, 0.f};
#pragma unroll
        for (int f = 0; f < 4; ++f) {
            half8 b = B8[(c * 4 + f) * 64 + lane];
            acc = __builtin_amdgcn_mfma_f32_16x16x32_f16(b, a[f], acc, 0, 0, 0);
        }
        if (row < n) {
            int r = 0;
            r = __builtin_amdgcn_cvt_pk_fp8_f32(acc[0], acc[1], r, 0);
            r = __builtin_amdgcn_cvt_pk_fp8_f32(acc[2], acc[3], r, 1);
            T32[((size_t)c * n + row) * 4 + quad] = (unsigned int)r;
        }
    }
}

// ---------------------------------------------------------------------------
// Aggregation, XCD dim-sliced: block handles slice s = blockIdx&7 (16 dims)
// for 4 nodes (1/wave). Lane (j = lane>>2, wd = lane&3): edge j of the
// 16-edge chunk, word wd of the slice -> ONE wave-gather covers 16 edges.
// Butterfly shfl over j-bits reduces; lanes 0-3 write 8B fp16 each.
// ---------------------------------------------------------------------------
__global__ __launch_bounds__(256) void agg_k(const unsigned int* __restrict__ T32,
                                             const int* __restrict__ rowptr,
                                             const int2* __restrict__ ew,
                                             const float* __restrict__ dis,
                                             const float* __restrict__ bias,
                                             __half* __restrict__ O, int n) {
    const int s    = blockIdx.x & 7;          // dim slice -> (heuristically) XCD
    const int ng   = blockIdx.x >> 3;
    const int lane = threadIdx.x & 63;
    const int j    = lane >> 2;               // edge within 16-chunk
    const int wd   = lane & 3;                // word within slice
    const int v = ng * 4 + (threadIdx.x >> 6);
    if (v >= n) return;

    const unsigned int* Ts = T32 + (size_t)s * n * 4;   // this slice's 1.6MB block
    float dv = dis[v];
    int e0 = rowptr[v], e1 = rowptr[v + 1];

    f32x4 acc = {0.f, 0.f, 0.f, 0.f};
    if (j == 0) {   // self term once per wd
        unsigned int r = Ts[(size_t)v * 4 + wd];
        f32x2 lo = __builtin_amdgcn_cvt_pk_f32_fp8((int)r, 0);
        f32x2 hi = __builtin_amdgcn_cvt_pk_f32_fp8((int)r, 1);
        float w = dv * dv;
        acc[0] += w * lo[0]; acc[1] += w * lo[1];
        acc[2] += w * hi[0]; acc[3] += w * hi[1];
    }

    for (int e = e0; e < e1; e += 16) {
        int idx = e + j;
        if (idx < e1) {
            int2 q = ew[idx];
            unsigned int r = Ts[(size_t)q.x * 4 + wd];
            float w = __int_as_float(q.y);
            f32x2 lo = __builtin_amdgcn_cvt_pk_f32_fp8((int)r, 0);
            f32x2 hi = __builtin_amdgcn_cvt_pk_f32_fp8((int)r, 1);
            acc[0] += w * lo[0]; acc[1] += w * lo[1];
            acc[2] += w * hi[0]; acc[3] += w * hi[1];
        }
    }

    // reduce over j (lane bits 2..5)
#pragma unroll
    for (int off = 4; off < 64; off <<= 1) {
#pragma unroll
        for (int i = 0; i < 4; ++i)
            acc[i] += __shfl_xor(acc[i], off, 64);
    }

    if (lane < 4) {   // lane == wd group j==0
        float4 b = ((const float4*)bias)[s * 4 + lane];
        __half2 o01 = __floats2half2_rn(fmaxf(acc[0] + b.x, 0.f), fmaxf(acc[1] + b.y, 0.f));
        __half2 o23 = __floats2half2_rn(fmaxf(acc[2] + b.z, 0.f), fmaxf(acc[3] + b.w, 0.f));
        *(int2*)(O + (size_t)v * DIM + s * 16 + lane * 4) = make_int2(*(int*)&o01, *(int*)&o23);
    }
}

// ---------------------------------------------------------------------------
// Global mean pool (fp16 in, fp32 out), split-parallel: grid (n_graphs, POOL_SPLIT)
// ---------------------------------------------------------------------------
__global__ __launch_bounds__(64) void pool_k(const __half* __restrict__ H,
                                             const int* __restrict__ batch,
                                             float* __restrict__ G, int n) {
    int g = blockIdx.x;
    int part = blockIdx.y;

    int lo = 0, hi = n;
    while (lo < hi) { int m = (lo + hi) >> 1; if (batch[m] < g) lo = m + 1; else hi = m; }
    int start = lo;
    lo = start; hi = n;
    while (lo < hi) { int m = (lo + hi) >> 1; if (batch[m] < g + 1) lo = m + 1; else hi = m; }
    int end = lo;
    int cnt = end - start;
    if (cnt <= 0) return;
    float inv = 1.0f / (float)cnt;

    int lane = threadIdx.x;
    const __half2* H2 = (const __half2*)H;
    float2 s = make_float2(0.f, 0.f);
    for (int v = start + part; v < end; v += POOL_SPLIT) {
        float2 h = __half22float2(H2[(size_t)v * 64 + lane]);
        s.x += h.x; s.y += h.y;
    }
    atomicAdd(&G[g * DIM + 2 * lane + 0], s.x * inv);
    atomicAdd(&G[g * DIM + 2 * lane + 1], s.y * inv);
}

// ---------------------------------------------------------------------------
// Head: y = relu(g@lin1+b1); logits = y@lin2+b2; out = log_softmax(logits)
// ---------------------------------------------------------------------------
__global__ __launch_bounds__(128) void head_k(const float* __restrict__ G,
                                              const float* __restrict__ l1w,
                                              const float* __restrict__ l1b,
                                              const float* __restrict__ l2w,
                                              const float* __restrict__ l2b,
                                              float* __restrict__ out) {
    int g = blockIdx.x;
    int j = threadIdx.x;
    __shared__ float gs[128];
    __shared__ float2 red[128];

    gs[j] = G[g * 128 + j];
    __syncthreads();

    float acc = l1b[j];
    for (int k = 0; k < 128; ++k) acc += gs[k] * l1w[k * 128 + j];
    float y = fmaxf(acc, 0.f);

    red[j] = make_float2(y * l2w[j * 2 + 0], y * l2w[j * 2 + 1]);
    __syncthreads();
    for (int s = 64; s > 0; s >>= 1) {
        if (j < s) {
            red[j].x += red[j + s].x;
            red[j].y += red[j + s].y;
        }
        __syncthreads();
    }
    if (j == 0) {
        float l0 = red[0].x + l2b[0];
        float l1 = red[0].y + l2b[1];
        float m = fmaxf(l0, l1);
        float lse = m + logf(expf(l0 - m) + expf(l1 - m));
        out[g * 2 + 0] = l0 - lse;
        out[g * 2 + 1] = l1 - lse;
    }
}

// ---------------------------------------------------------------------------
// Launch
// ---------------------------------------------------------------------------
extern "C" void kernel_launch(void* const* d_in, const int* in_sizes, int n_in,
                              void* d_out, int out_size, void* d_ws, size_t ws_size,
                              hipStream_t stream) {
    const float* x       = (const float*)d_in[0];
    const int*   ei      = (const int*)d_in[1];
    const int*   batch   = (const int*)d_in[2];
    const float* conv_w  = (const float*)d_in[3];
    const float* conv_b  = (const float*)d_in[4];
    const float* lin1_w  = (const float*)d_in[5];
    const float* lin1_b  = (const float*)d_in[6];
    const float* lin2_w  = (const float*)d_in[7];
    const float* lin2_b  = (const float*)d_in[8];
    float* out = (float*)d_out;

    const int n = in_sizes[0] / DIM;      // 100000
    const int E = in_sizes[1] / 2;        // 1600000
    const int n_graphs = 128;
    const int NBIN = (n + (1 << BINSH) - 1) >> BINSH;   // 98 dst-bins

    const int* src = ei;
    const int* dst = ei + E;

    // workspace layout (all 256B aligned)
    char* p = (char*)d_ws;
    auto alloc = [&](size_t bytes) {
        char* r = p;
        p += (bytes + 255) & ~(size_t)255;
        return r;
    };
    __half*        bufH    = (__half*)alloc((size_t)n * DIM * 2);       // agg output (fp16)
    unsigned int*  bufT    = (unsigned int*)alloc((size_t)n * DIM);     // gemm output (fp8, slice-major)
    float*         dis     = (float*)alloc((size_t)n * 4);
    int*           rowptr  = (int*)alloc((size_t)(n + 1) * 4);
    int*           binsize = (int*)alloc(128 * 4);
    int*           binbase = (int*)alloc(132 * 4);
    int*           bincur  = (int*)alloc((size_t)NBIN * 16 * 4);
    int2*          tmp     = (int2*)alloc((size_t)E * 8);               // binned {src,dst}
    int2*          ew      = (int2*)alloc((size_t)E * 8);               // CSR {col, wgt}
    float*         gbuf    = (float*)alloc((size_t)n_graphs * DIM * 4);
    _Float16*      bp      = (_Float16*)alloc((size_t)3 * 2048 * 8 * 2);
    (void)ws_size;

    const int binBlocks = (E + EPB - 1) / EPB;      // 98

    hipMemsetAsync(binsize, 0, 128 * 4, stream);
    hipMemsetAsync(gbuf, 0, (size_t)n_graphs * DIM * 4, stream);
    wpack_k<<<24, 256, 0, stream>>>(conv_w, bp);
    bincount_k<<<binBlocks, 256, 0, stream>>>(dst, binsize, E, NBIN);
    binscan2_k<<<1, 128, 0, stream>>>(binsize, binbase, bincur, NBIN, E);
    bin_k<<<binBlocks, 256, 0, stream>>>(src, dst, bincur, tmp, E, NBIN);
    rowcnt_k<<<NBIN, 256, 0, stream>>>(tmp, binbase, rowptr, dis, n, E, NBIN);
    fill2_k<<<NBIN, 256, 0, stream>>>(tmp, rowptr, dis, ew, n);

    const int gemmBlocks = (n + 63) / 64;
    const int aggBlocks = ((n + 3) / 4) * 8;   // x8 dim slices

    // layer 0: x (fp32) -> bufT(fp8 slice-major) -> bufH(fp16)
    gemm_k<false><<<gemmBlocks, 256, 0, stream>>>((const void*)x, bp + 0 * 16384, bufT, n);
    agg_k<<<aggBlocks, 256, 0, stream>>>(bufT, rowptr, ew, dis, conv_b + 0 * DIM, bufH, n);
    // layer 1
    gemm_k<true><<<gemmBlocks, 256, 0, stream>>>((const void*)bufH, bp + 1 * 16384, bufT, n);
    agg_k<<<aggBlocks, 256, 0, stream>>>(bufT, rowptr, ew, dis, conv_b + 1 * DIM, bufH, n);
    // layer 2
    gemm_k<true><<<gemmBlocks, 256, 0, stream>>>((const void*)bufH, bp + 2 * 16384, bufT, n);
    agg_k<<<aggBlocks, 256, 0, stream>>>(bufT, rowptr, ew, dis, conv_b + 2 * DIM, bufH, n);

    dim3 pgrid(n_graphs, POOL_SPLIT);
    pool_k<<<pgrid, 64, 0, stream>>>(bufH, batch, gbuf, n);
    head_k<<<n_graphs, 128, 0, stream>>>(gbuf, lin1_w, lin1_b, lin2_w, lin2_b, out);
}